// Round 11
// baseline (108.867 us; speedup 1.0000x reference)
//
#include <hip/hip_runtime.h>
#include <hip/hip_fp16.h>

// SilkNNUE R21 — R20 + non-temporal gather loads (L1-bypass probe).
//   R20 post-mortem: 1-ahead pipeline ~null => address pipe already
//   saturated. Measured: 131K lane-addr/CU in ~91K cyc = 1.45 addr/cyc
//   (2.8 cyc per 64B miss line). Gather is at the algorithmic floor
//   (32 x 128B segments per training row, one per feature). Remaining
//   hypothesis: L1 allocation/MSHR serialization on always-miss lines.
//   R21: __builtin_nontemporal_load on the 4 table loads (emits nt flag,
//   bypasses L1 allocation; table stays L2-resident, no reuse lost).
//   Null branch => intrinsic line rate => roofline.
//   Chain: absmax_partial(+W) -> prep_q8 -> nnue_q8. Dense MFMA unchanged.

typedef _Float16 h2v_t  __attribute__((ext_vector_type(2)));
typedef _Float16 half8  __attribute__((ext_vector_type(8)));
typedef float    f32x4  __attribute__((ext_vector_type(4)));
typedef unsigned u32x4  __attribute__((ext_vector_type(4)));

constexpr int RPB    = 64;    // rows per block (main kernel)
constexpr int NSLOTS = 512;   // absmax partial slots

// ---- pass 1: per-block absmax partials + W2/W3 -> fp16 --------------------
__global__ __launch_bounds__(256) void absmax_partial(
    const float4* __restrict__ emb4, float* __restrict__ slots,
    const float* __restrict__ W2, const float* __restrict__ W3,
    _Float16* __restrict__ W2h, _Float16* __restrict__ W3h, int n4)
{
    __shared__ float red[4];
    const int tid = threadIdx.x;
    const int i0  = blockIdx.x * 256 + tid;
    float m = 0.f;
    const int stride = NSLOTS * 256;
    for (int i = i0; i < n4; i += stride) {
        float4 v = emb4[i];
        m = fmaxf(m, fmaxf(fmaxf(fabsf(v.x), fabsf(v.y)),
                           fmaxf(fabsf(v.z), fabsf(v.w))));
    }
    #pragma unroll
    for (int s = 1; s < 64; s <<= 1)
        m = fmaxf(m, __shfl_xor(m, s));
    if ((tid & 63) == 0) red[tid >> 6] = m;
    // W conversion is amax-independent; fill idle slots of early blocks
    if (i0 < 4096) W2h[i0] = (_Float16)W2[i0];
    if (i0 < 2048) W3h[i0] = (_Float16)W3[i0];
    __syncthreads();
    if (tid == 0)
        slots[blockIdx.x] = fmaxf(fmaxf(red[0], red[1]), fmaxf(red[2], red[3]));
}

// ---- pass 2: reduce slots + quantize emb -> u8 ----------------------------
__global__ __launch_bounds__(256) void prep_q8(
    const float4* __restrict__ emb4, unsigned* __restrict__ emb8,
    const float* __restrict__ slots, float* __restrict__ amax_out)
{
    __shared__ float red[4];
    const int tid = threadIdx.x;
    // block-local reduce of the 512 partials (2KB, L2-hot)
    float m = fmaxf(slots[tid], slots[tid + 256]);
    #pragma unroll
    for (int s = 1; s < 64; s <<= 1)
        m = fmaxf(m, __shfl_xor(m, s));
    if ((tid & 63) == 0) red[tid >> 6] = m;
    __syncthreads();
    const float amax = fmaxf(fmaxf(fmaxf(red[0], red[1]),
                                   fmaxf(red[2], red[3])), 1e-20f);
    const float qs = 127.f / amax;

    const int i = blockIdx.x * 256 + tid;
    if (i == 0) *amax_out = amax;
    if (i < 7425 * 32) {
        unsigned w = 0x80808080u;              // zero row 7424: q=0
        if (i < 7424 * 32) {
            float4 v = emb4[i];
            int q0 = min(127, max(-127, (int)rintf(v.x * qs)));
            int q1 = min(127, max(-127, (int)rintf(v.y * qs)));
            int q2 = min(127, max(-127, (int)rintf(v.z * qs)));
            int q3 = min(127, max(-127, (int)rintf(v.w * qs)));
            // byte order (d0,d2,d1,d3): lo-mask slots = dims (4j,4j+1),
            // hi-perm slots = dims (4j+2,4j+3)
            w = (unsigned)(q0 + 128)
              | ((unsigned)(q2 + 128) << 8)
              | ((unsigned)(q1 + 128) << 16)
              | ((unsigned)(q3 + 128) << 24);
        }
        emb8[i] = w;
    }
}

__device__ inline unsigned cvt_pair(unsigned w, float sc, float cb) {
    float f0 = (float)(w & 0xffffu) * sc + cb;
    float f1 = (float)(w >> 16)     * sc + cb;
    h2v_t h;
    h[0] = (_Float16)fmaxf(f0, 0.f);
    h[1] = (_Float16)fmaxf(f1, 0.f);
    return __builtin_bit_cast(unsigned, h);
}

__device__ inline u32x4 nt_load(const char* p) {
    return __builtin_nontemporal_load((const u32x4*)p);
}

// ---------------- fused kernel (int8, nt gather, pipelined) ----------------
__global__ __launch_bounds__(256, 6) void nnue_q8(
    const int*      __restrict__ x,      // (N,32)
    const unsigned* __restrict__ emb8,   // (7425,128) u8 permuted
    const _Float16* __restrict__ W2h,    // (32,128) fp16
    const _Float16* __restrict__ W3h,    // (32,64) fp16
    const float*    __restrict__ b2,
    const float*    __restrict__ b3,
    const float*    __restrict__ W4,     // (64,)
    const float*    __restrict__ amaxp,
    float*          __restrict__ out, int n)
{
    // per-wave: hT = 16 rows x 16 uint4 (swizzled), later aliased by a2 tile
    __shared__ __align__(16) char hmem[4][4096];   // 16384 B
    // per-wave packed u16 indices
    __shared__ __align__(16) char xmem[4][1024];   //  4096 B  (total 20480)

    const int tid  = threadIdx.x;
    const int lane = tid & 63;
    const int wave = tid >> 6;
    const int row0 = blockIdx.x * RPB;
    const int wrow0 = __builtin_amdgcn_readfirstlane(row0 + wave * 16);

    const float amax = *amaxp;
    const float sc = amax * (1.f / 127.f);
    const float cb = -4096.f * sc;      // bias removal: 32 features x 128

    const int g    = lane >> 4;         // 0..3
    const int sub  = lane & 15;         // 0..15
    const int s7   = sub & 7;           // 16B chunk of the 128B int8 row
    const bool sHi = (sub >= 8);
    const unsigned chunkOff = (unsigned)s7 * 16u;
    const char* embb = (const char*)emb8;

    unsigned short* xw = (unsigned short*)&xmem[wave][0];

    // ---- stage indices packed u16 (features 29..31 -> zero row 7424) ------
    {
        const int4* xb = (const int4*)(x + (size_t)wrow0 * 32);
        int4 a = xb[lane * 2];
        int4 b = xb[lane * 2 + 1];
        if ((lane & 3) == 3) { b.y = 7424; b.z = 7424; b.w = 7424; }
        uint4 pk;
        pk.x = ((unsigned)a.x & 0xffffu) | ((unsigned)a.y << 16);
        pk.y = ((unsigned)a.z & 0xffffu) | ((unsigned)a.w << 16);
        pk.z = ((unsigned)b.x & 0xffffu) | ((unsigned)b.y << 16);
        pk.w = ((unsigned)b.z & 0xffffu) | ((unsigned)b.w << 16);
        ((uint4*)xw)[lane] = pk;
    }
    // same-wave DS ordering; no barriers anywhere in this kernel.

    const bool gHi  = (g >= 2);
    const bool gOdd = (g & 1);
    // lane finally owns fp16-word wIdx = 8*s7 + 2*g + sHi of each row
    const int wIdx = 8 * s7 + 2 * g + (sHi ? 1 : 0);
    const int granule = wIdx >> 2;          // 16B granule 0..15
    const int wInG    = (wIdx & 3) * 4;     // byte within granule
    const int fOff    = g + (sHi ? 4 : 0);  // feature offset within octet

    // ---- gather: 4 x nt-uint4 per row, 1-row-ahead pipeline ---------------
    u32x4 c0, c1, c2, c3;
    {
        const unsigned short* xr = xw + fOff;
        c0 = nt_load(embb + (((unsigned)xr[0]  << 7) + chunkOff));
        c1 = nt_load(embb + (((unsigned)xr[8]  << 7) + chunkOff));
        c2 = nt_load(embb + (((unsigned)xr[16] << 7) + chunkOff));
        c3 = nt_load(embb + (((unsigned)xr[24] << 7) + chunkOff));
    }
    #pragma unroll
    for (int r = 0; r < 16; ++r) {
        u32x4 n0, n1, n2, n3;
        if (r < 15) {
            const unsigned short* xr = xw + (r + 1) * 32 + fOff;
            n0 = nt_load(embb + (((unsigned)xr[0]  << 7) + chunkOff));
            n1 = nt_load(embb + (((unsigned)xr[8]  << 7) + chunkOff));
            n2 = nt_load(embb + (((unsigned)xr[16] << 7) + chunkOff));
            n3 = nt_load(embb + (((unsigned)xr[24] << 7) + chunkOff));
            // pin: next-row loads must be issued before this row's combine
            __builtin_amdgcn_sched_barrier(0);
        }
        // accumulate 4 features into 8 accs (16-bit slots, exact, max 8160)
        unsigned a0 = 0, a1 = 0, a2 = 0, a3 = 0, a4 = 0, a5 = 0, a6 = 0, a7 = 0;
        {
            a0 += c0.x & 0x00ff00ffu;
            a1 += __builtin_amdgcn_perm(0u, c0.x, 0x0c030c01u);
            a2 += c0.y & 0x00ff00ffu;
            a3 += __builtin_amdgcn_perm(0u, c0.y, 0x0c030c01u);
            a4 += c0.z & 0x00ff00ffu;
            a5 += __builtin_amdgcn_perm(0u, c0.z, 0x0c030c01u);
            a6 += c0.w & 0x00ff00ffu;
            a7 += __builtin_amdgcn_perm(0u, c0.w, 0x0c030c01u);

            a0 += c1.x & 0x00ff00ffu;
            a1 += __builtin_amdgcn_perm(0u, c1.x, 0x0c030c01u);
            a2 += c1.y & 0x00ff00ffu;
            a3 += __builtin_amdgcn_perm(0u, c1.y, 0x0c030c01u);
            a4 += c1.z & 0x00ff00ffu;
            a5 += __builtin_amdgcn_perm(0u, c1.z, 0x0c030c01u);
            a6 += c1.w & 0x00ff00ffu;
            a7 += __builtin_amdgcn_perm(0u, c1.w, 0x0c030c01u);

            a0 += c2.x & 0x00ff00ffu;
            a1 += __builtin_amdgcn_perm(0u, c2.x, 0x0c030c01u);
            a2 += c2.y & 0x00ff00ffu;
            a3 += __builtin_amdgcn_perm(0u, c2.y, 0x0c030c01u);
            a4 += c2.z & 0x00ff00ffu;
            a5 += __builtin_amdgcn_perm(0u, c2.z, 0x0c030c01u);
            a6 += c2.w & 0x00ff00ffu;
            a7 += __builtin_amdgcn_perm(0u, c2.w, 0x0c030c01u);

            a0 += c3.x & 0x00ff00ffu;
            a1 += __builtin_amdgcn_perm(0u, c3.x, 0x0c030c01u);
            a2 += c3.y & 0x00ff00ffu;
            a3 += __builtin_amdgcn_perm(0u, c3.y, 0x0c030c01u);
            a4 += c3.z & 0x00ff00ffu;
            a5 += __builtin_amdgcn_perm(0u, c3.z, 0x0c030c01u);
            a6 += c3.w & 0x00ff00ffu;
            a7 += __builtin_amdgcn_perm(0u, c3.w, 0x0c030c01u);
        }
        // L1 (xor 32, g-bit1): keep words {0,1} if g<2 else {2,3}
        unsigned b0, b1, b2, b3;
        {
            const unsigned s0 = gHi ? a0 : a4;
            const unsigned s1 = gHi ? a1 : a5;
            const unsigned s2 = gHi ? a2 : a6;
            const unsigned s3 = gHi ? a3 : a7;
            b0 = (gHi ? a4 : a0) + (unsigned)__shfl_xor((int)s0, 32);
            b1 = (gHi ? a5 : a1) + (unsigned)__shfl_xor((int)s1, 32);
            b2 = (gHi ? a6 : a2) + (unsigned)__shfl_xor((int)s2, 32);
            b3 = (gHi ? a7 : a3) + (unsigned)__shfl_xor((int)s3, 32);
        }
        // L2 (xor 16, g-bit0): keep one word (lo/hi acc pair)
        unsigned cc0, cc1;
        {
            const unsigned s0 = gOdd ? b0 : b2;
            const unsigned s1 = gOdd ? b1 : b3;
            cc0 = (gOdd ? b2 : b0) + (unsigned)__shfl_xor((int)s0, 16);
            cc1 = (gOdd ? b3 : b1) + (unsigned)__shfl_xor((int)s1, 16);
        }
        // L3 (xor 8, sub-bit3): keep lo (sub<8) or hi (sub>=8) dim-pair
        const unsigned sz = sHi ? cc0 : cc1;
        const unsigned Z  = (sHi ? cc1 : cc0) + (unsigned)__shfl_xor((int)sz, 8);
        // full-wave store: fp16-word wIdx of row r, swizzled granule
        const int byteOff = r * 256 + (((granule ^ (r & 7)) << 4) | wInG);
        *(unsigned*)(&hmem[wave][byteOff]) = cvt_pair(Z, sc, cb);

        if (r < 15) { c0 = n0; c1 = n1; c2 = n2; c3 = n3; }
    }

    // ================= dense (per-wave MFMA, same wave's 16 rows) ==========
    const uint4* hT = (const uint4*)&hmem[wave][0];
    const int q  = lane >> 4;     // k-quad
    const int nn = lane & 15;     // A row m / B col n / C col n

    half8 bw2[2][4];
    #pragma unroll
    for (int nt = 0; nt < 2; ++nt)
        #pragma unroll
        for (int kk = 0; kk < 4; ++kk)
            bw2[nt][kk] = __builtin_bit_cast(half8,
                *(const uint4*)((const char*)W2h +
                    ((nt * 16 + nn) * 128 + kk * 32 + q * 8) * 2));

    half8 af[4];
    #pragma unroll
    for (int kk = 0; kk < 4; ++kk)
        af[kk] = __builtin_bit_cast(half8,
            hT[nn * 16 + ((4 * kk + q) ^ (nn & 7))]);

    f32x4 acc0 = {0.f, 0.f, 0.f, 0.f}, acc1 = {0.f, 0.f, 0.f, 0.f};
    #pragma unroll
    for (int kk = 0; kk < 4; ++kk) {
        acc0 = __builtin_amdgcn_mfma_f32_16x16x32_f16(af[kk], bw2[0][kk], acc0, 0, 0, 0);
        acc1 = __builtin_amdgcn_mfma_f32_16x16x32_f16(af[kk], bw2[1][kk], acc1, 0, 0, 0);
    }
    const float bb0 = b2[nn], bb1 = b2[16 + nn];

    // CReLU + transpose via LDS (stride 68 halfs). a2 aliases hT:
    // all hT (af) reads completed above, same-wave program order.
    _Float16* a2p = (_Float16*)&hmem[wave][0];
    #pragma unroll
    for (int r = 0; r < 4; ++r) {
        const float v0 = acc0[r] + bb0;
        const float v1 = acc1[r] + bb1;
        const int m = q * 4 + r;
        a2p[m * 68 + nn]      = (_Float16)fmaxf(v0, 0.f);
        a2p[m * 68 + 16 + nn] = (_Float16)fmaxf(v1, 0.f);
        a2p[m * 68 + 32 + nn] = (_Float16)fmaxf(-v0, 0.f);
        a2p[m * 68 + 48 + nn] = (_Float16)fmaxf(-v1, 0.f);
    }

    half8 bw3[2][2];
    #pragma unroll
    for (int nt = 0; nt < 2; ++nt)
        #pragma unroll
        for (int kk = 0; kk < 2; ++kk)
            bw3[nt][kk] = __builtin_bit_cast(half8,
                *(const uint4*)((const char*)W3h +
                    ((nt * 16 + nn) * 64 + kk * 32 + q * 8) * 2));

    half8 a2f[2];
    #pragma unroll
    for (int kk = 0; kk < 2; ++kk) {
        const _Float16* pp = &a2p[nn * 68 + kk * 32 + q * 8];
        half8 t;
        #pragma unroll
        for (int j = 0; j < 8; ++j) t[j] = pp[j];
        a2f[kk] = t;
    }

    f32x4 acc30 = {0.f, 0.f, 0.f, 0.f}, acc31 = {0.f, 0.f, 0.f, 0.f};
    #pragma unroll
    for (int kk = 0; kk < 2; ++kk) {
        acc30 = __builtin_amdgcn_mfma_f32_16x16x32_f16(a2f[kk], bw3[0][kk], acc30, 0, 0, 0);
        acc31 = __builtin_amdgcn_mfma_f32_16x16x32_f16(a2f[kk], bw3[1][kk], acc31, 0, 0, 0);
    }
    const float bb30 = b3[nn], bb31 = b3[16 + nn];

    const float w4a = W4[nn],      w4b = W4[16 + nn];
    const float w4c = W4[32 + nn], w4d = W4[48 + nn];
    float o[4];
    #pragma unroll
    for (int r = 0; r < 4; ++r) {
        const float v0 = acc30[r] + bb30;
        const float v1 = acc31[r] + bb31;
        o[r] = fmaxf(v0, 0.f) * w4a + fmaxf(-v0, 0.f) * w4c
             + fmaxf(v1, 0.f) * w4b + fmaxf(-v1, 0.f) * w4d;
    }
    #pragma unroll
    for (int s = 1; s < 16; s <<= 1) {
        #pragma unroll
        for (int r = 0; r < 4; ++r) o[r] += __shfl_xor(o[r], s);
    }
    if (nn == 0) {
        #pragma unroll
        for (int r = 0; r < 4; ++r) {
            const int row = wrow0 + q * 4 + r;
            if (row < n) out[row] = o[r];
        }
    }
}

// ---------------- fallback (fp16 table + fp32-weight fused) ----------------
__global__ __launch_bounds__(256) void prep_fp16(
    const float* __restrict__ emb, __half2* __restrict__ emb16,
    int npairs_real, int npairs_tot)
{
    int i = blockIdx.x * blockDim.x + threadIdx.x;
    if (i < npairs_tot) {
        float2 v = make_float2(0.f, 0.f);
        if (i < npairs_real) v = ((const float2*)emb)[i];
        emb16[i] = __floats2half2_rn(v.x, v.y);
    }
}

__global__ __launch_bounds__(256) void nnue_fused(
    const int*    __restrict__ x,
    const __half* __restrict__ emb16,
    const float*  __restrict__ W2, const float* __restrict__ b2,
    const float*  __restrict__ W3, const float* __restrict__ b3,
    const float*  __restrict__ W4,
    float*        __restrict__ out, int n)
{
    __shared__ int     xlds[4][512];
    __shared__ __half2 hbuf[64][65];
    __shared__ float   h2T[32 * 64];
    __shared__ float   obuf[4][64];

    const int tid  = threadIdx.x;
    const int lane = tid & 63;
    const int wave = tid >> 6;
    const int row0 = blockIdx.x * RPB;
    const int wrow0 = __builtin_amdgcn_readfirstlane(row0 + wave * 16);
    const int g   = lane >> 4;
    const int sub = lane & 15;
    const unsigned subOff = (unsigned)sub * 16u;

    {
        const int4* xb = (const int4*)(x + (size_t)wrow0 * 32);
        int4 a = xb[lane * 2];
        int4 b = xb[lane * 2 + 1];
        if ((lane & 3) == 3) { b.y = 7424; b.z = 7424; b.w = 7424; }
        ((int4*)&xlds[wave][0])[lane * 2]     = a;
        ((int4*)&xlds[wave][0])[lane * 2 + 1] = b;
    }

    #pragma unroll 4
    for (int r = 0; r < 16; ++r) {
        const int* xrow = &xlds[wave][r * 32 + g];
        uint4 v[8];
        #pragma unroll
        for (int b = 0; b < 8; ++b) {
            const int idx = xrow[4 * b];
            const unsigned off = ((unsigned)idx << 8) + subOff;
            v[b] = *(const uint4*)((const char*)emb16 + off);
        }
        h2v_t hacc[4];
        #pragma unroll
        for (int q = 0; q < 4; ++q) hacc[q] = (h2v_t)0;
        #pragma unroll
        for (int b = 0; b < 8; ++b) {
            hacc[0] += __builtin_bit_cast(h2v_t, v[b].x);
            hacc[1] += __builtin_bit_cast(h2v_t, v[b].y);
            hacc[2] += __builtin_bit_cast(h2v_t, v[b].z);
            hacc[3] += __builtin_bit_cast(h2v_t, v[b].w);
        }
        #pragma unroll
        for (int q = 0; q < 4; ++q) {
            unsigned u = __builtin_bit_cast(unsigned, hacc[q]);
            h2v_t t = __builtin_bit_cast(h2v_t, u);
            t += __builtin_bit_cast(h2v_t, (unsigned)__shfl_xor((int)u, 16));
            unsigned u2 = __builtin_bit_cast(unsigned, t);
            t += __builtin_bit_cast(h2v_t, (unsigned)__shfl_xor((int)u2, 32));
            hacc[q] = __builtin_elementwise_max(t, (h2v_t)0);
        }
        if (g == 0) {
            const int row = wave * 16 + r;
            #pragma unroll
            for (int q = 0; q < 4; ++q)
                hbuf[row][sub * 4 + q] = __builtin_bit_cast(__half2, hacc[q]);
        }
    }
    __syncthreads();

    {
        const int j0 = wave * 8;
        const int rr = lane;
        float acc[8];
        #pragma unroll
        for (int j = 0; j < 8; ++j) acc[j] = b2[j0 + j];
        #pragma unroll
        for (int d2 = 0; d2 < 64; ++d2) {
            const __half2 hv = hbuf[rr][d2];
            const float vx = __low2float(hv), vy = __high2float(hv);
            #pragma unroll
            for (int j = 0; j < 8; ++j) {
                const float* w = W2 + (size_t)(j0 + j) * 128 + d2 * 2;
                acc[j] = fmaf(vx, w[0], acc[j]);
                acc[j] = fmaf(vy, w[1], acc[j]);
            }
        }
        #pragma unroll
        for (int j = 0; j < 8; ++j) h2T[(j0 + j) * 64 + rr] = acc[j];
    }
    __syncthreads();

    {
        const int j0 = wave * 8;
        const int rr = lane;
        float h2v[32];
        #pragma unroll
        for (int k = 0; k < 32; ++k) h2v[k] = h2T[k * 64 + rr];
        float acc[8];
        #pragma unroll
        for (int j = 0; j < 8; ++j) acc[j] = b3[j0 + j];
        #pragma unroll
        for (int k = 0; k < 32; ++k) {
            const float pz = fmaxf(h2v[k], 0.f);
            const float mz = fmaxf(-h2v[k], 0.f);
            #pragma unroll
            for (int j = 0; j < 8; ++j) {
                const float* w = W3 + (size_t)(j0 + j) * 64;
                acc[j] = fmaf(pz, w[k],      acc[j]);
                acc[j] = fmaf(mz, w[32 + k], acc[j]);
            }
        }
        float o = 0.f;
        #pragma unroll
        for (int j = 0; j < 8; ++j) {
            const int jj = j0 + j;
            o = fmaf(fmaxf(acc[j], 0.f),  W4[jj],      o);
            o = fmaf(fmaxf(-acc[j], 0.f), W4[32 + jj], o);
        }
        obuf[wave][rr] = o;
    }
    __syncthreads();

    if (tid < 64) {
        const int row = row0 + tid;
        if (row < n)
            out[row] = obuf[0][tid] + obuf[1][tid] + obuf[2][tid] + obuf[3][tid];
    }
}

extern "C" void kernel_launch(void* const* d_in, const int* in_sizes, int n_in,
                              void* d_out, int out_size, void* d_ws, size_t ws_size,
                              hipStream_t stream) {
    const int*   x   = (const int*)  d_in[0];
    const float* emb = (const float*)d_in[1];
    const float* W2  = (const float*)d_in[2];
    const float* b2  = (const float*)d_in[3];
    const float* W3  = (const float*)d_in[4];
    const float* b3  = (const float*)d_in[5];
    const float* W4  = (const float*)d_in[6];
    float* out = (float*)d_out;
    const int n = out_size;                 // 131072 rows

    // workspace layout (16B-aligned sections)
    const size_t emb8_bytes = (size_t)7425 * 128;           // 950,400
    const size_t w2h_off    = emb8_bytes;                   // +8192
    const size_t w3h_off    = w2h_off + 8192;               // +4096
    const size_t slots_off  = w3h_off + 4096;               // +2048 (512 f32)
    const size_t amax_off   = slots_off + 2048;             // +16
    const size_t need       = amax_off + 16;

    if (ws_size >= need) {
        unsigned*     emb8  = (unsigned*)d_ws;
        _Float16*     W2h   = (_Float16*)((char*)d_ws + w2h_off);
        _Float16*     W3h   = (_Float16*)((char*)d_ws + w3h_off);
        float*        slots = (float*)((char*)d_ws + slots_off);
        float*        amaxp = (float*)((char*)d_ws + amax_off);
        const float4* emb4  = (const float4*)emb;

        const int n4 = 7424 * 32;   // 237,568 float4s
        hipLaunchKernelGGL(absmax_partial, dim3(NSLOTS), dim3(256), 0, stream,
                           emb4, slots, W2, W3, W2h, W3h, n4);

        const int nq = 7425 * 32;   // 237,600 u32s -> 929 blocks
        hipLaunchKernelGGL(prep_q8, dim3((nq + 255) / 256), dim3(256),
                           0, stream, emb4, emb8, slots, amaxp);

        hipLaunchKernelGGL(nnue_q8, dim3((n + RPB - 1) / RPB), dim3(256),
                           0, stream, x, emb8, W2h, W3h, b2, b3, W4,
                           amaxp, out, n);
    } else {
        // legacy fallback: fp16 table + fp32-weight fused kernel
        __half2* emb16 = (__half2*)d_ws;
        const int npairs_real = 7424 * 64;
        const int npairs_tot  = 7425 * 64;
        hipLaunchKernelGGL(prep_fp16, dim3((npairs_tot + 255) / 256), dim3(256),
                           0, stream, emb, emb16, npairs_real, npairs_tot);
        hipLaunchKernelGGL(nnue_fused, dim3((n + RPB - 1) / RPB), dim3(256),
                           0, stream, x, (const __half*)emb16, W2, b2, W3, b3,
                           W4, out, n);
    }
}